// Round 8
// baseline (285.732 us; speedup 1.0000x reference)
//
#include <hip/hip_runtime.h>

// Problem constants
#define NB 256
#define NDF 768
#define NQ 96
#define NS 361
#define LDT 40        // K1 staging stride (bf16 elems): 80B rows, 16B-aligned b128 frags
#define LDP 392       // K2 attn LDS stride (bf16 elems): 784B rows, 16B-aligned
#define WSROW 368     // ws logits row stride (bf16 elems): 184 dwords, 16B-aligned
#define CSROW 368     // ws ctx row stride (bf16 elems): 184 dwords, 16B-aligned
#define WS_LOG_BYTES ((size_t)NB * NQ * WSROW * 2)
#define WS_CTX_BYTES ((size_t)NB * NDF * CSROW * 2)
#define WS_FULL_BYTES (WS_LOG_BYTES + WS_CTX_BYTES)

typedef short bf16x8_t __attribute__((ext_vector_type(8)));
typedef float f32x4_t __attribute__((ext_vector_type(4)));
typedef float f32x4u_t __attribute__((ext_vector_type(4), aligned(4)));
typedef float f32x2u_t __attribute__((ext_vector_type(2), aligned(4)));
typedef unsigned int u32x2_t __attribute__((ext_vector_type(2)));
typedef unsigned int u32x4_t __attribute__((ext_vector_type(4)));

// [b.hi16 | a.hi16] -> one dword (1 v_perm_b32); trunc-to-bf16 pack
__device__ __forceinline__ unsigned pack_hi(unsigned b_, unsigned a_) {
    return __builtin_amdgcn_perm(b_, a_, 0x07060302u);
}
__device__ __forceinline__ unsigned short f2bf(float x) {   // RNE
    unsigned u = __float_as_uint(x);
    u += 0x7FFFu + ((u >> 16) & 1u);
    return (unsigned short)(u >> 16);
}
__device__ __forceinline__ float bf2f(unsigned short h) {
    return __uint_as_float(((unsigned)h) << 16);
}

// LDS-only barrier: orders LDS ops (lgkmcnt) but does NOT drain vmcnt.
__device__ __forceinline__ void block_sync_lds() {
    __builtin_amdgcn_sched_barrier(0);
    asm volatile("s_waitcnt lgkmcnt(0)" ::: "memory");
    __builtin_amdgcn_sched_barrier(0);
    __builtin_amdgcn_s_barrier();
    __builtin_amdgcn_sched_barrier(0);
}

// ================= K1: GEMM1 (split-bf16) + softmax over q =================
// grid NB*4 (batch, s-quarter of 96), 384 thr = 6 waves; wave: 1 s-tile x 6 q-tiles.
// LDS 30.7KB + acc 24 VGPR -> 4 blocks/CU x 6 waves = 24 waves/CU (2x round-7 TLP).
// MODE 0: softmaxq*4 fp32 -> Aout.  MODE 1: bf16 logits2 -> ws.
// MODE 2: MODE1 + relay ctx bf16 [d][s] -> ws (coalesced dword stores).
template<int MODE>
__global__ __launch_bounds__(384, 6) void k1_gemm1_softmaxq(
    const float* __restrict__ Qg, const float* __restrict__ Cg,
    unsigned short* __restrict__ WsLog, unsigned* __restrict__ WsCtxD,
    float* __restrict__ AoutF)
{
    __shared__ unsigned short sQhi[NQ * LDT];
    __shared__ unsigned short sQlo[NQ * LDT];
    __shared__ unsigned short sShi[NQ * LDT];
    __shared__ unsigned short sSlo[NQ * LDT];

    const int b = blockIdx.x >> 2;
    const int h = blockIdx.x & 3;
    const int tid = threadIdx.x;       // 0..383
    const int wv = tid >> 6;           // 0..5
    const int lane = tid & 63;
    const int ll = lane & 15;
    const int lg = lane >> 4;
    const int s0 = 96 * h;
    // staging geometry (same for Q and C): thread owns column pair (2qp, 2qp+1)
    // and one k-quad kq8 (4 consecutive k rows). 8 quads x 48 pairs = 32k x 96cols.
    const int qp  = tid % 48;
    const int kq8 = tid / 48;          // 0..7
    const int sA0 = s0 + 2 * qp;
    const bool ok0 = (sA0 < NS);
    const bool ok1 = (sA0 + 1 < NS);
    const int wsCol = 48 * h + qp;     // ctx-ws dword column
    const bool wok = (MODE == 2) && (wsCol < 184);

    const float* __restrict__ qg = Qg + (size_t)b * NDF * NQ;   // [768][96]
    const float* __restrict__ cg = Cg + (size_t)b * NDF * NS;   // [768][361]
    unsigned* __restrict__ wscd = (MODE == 2) ? (WsCtxD + (size_t)b * NDF * 184) : nullptr;

    f32x4_t acc[6];
#pragma unroll
    for (int i = 0; i < 6; ++i) acc[i] = (f32x4_t)0.0f;

    float RQa[8], RQb[8], RCa[8], RCb[8];   // [k-row j][col s1] -> R[2j+s1]

#define LOADQ(K0, R) { \
    _Pragma("unroll") \
    for (int j = 0; j < 4; ++j) { \
        f32x2u_t v = *(const f32x2u_t*)(qg + ((K0) + 4 * kq8 + j) * NQ + 2 * qp); \
        R[2*j+0] = v[0]; R[2*j+1] = v[1]; } }

#define LOADC(K0, R) { \
    _Pragma("unroll") \
    for (int j = 0; j < 4; ++j) { \
        const float* pj = cg + ((K0) + 4 * kq8 + j) * NS + sA0; \
        f32x2u_t v; \
        if (ok1) { v = *(const f32x2u_t*)pj; } \
        else { v[0] = ok0 ? pj[0] : 0.0f; v[1] = 0.0f; } \
        R[2*j+0] = v[0]; R[2*j+1] = v[1]; } }

// store column pair into transposed hi/lo LDS tiles; DSTH/DSTL are base ptrs
#define STORE2(R, DSTH, DSTL) { \
    _Pragma("unroll") \
    for (int s1 = 0; s1 < 2; ++s1) { \
        unsigned u0 = __float_as_uint(R[0+s1]), u1 = __float_as_uint(R[2+s1]); \
        unsigned u2 = __float_as_uint(R[4+s1]), u3 = __float_as_uint(R[6+s1]); \
        float l0 = R[0+s1] - __uint_as_float(u0 & 0xFFFF0000u); \
        float l1 = R[2+s1] - __uint_as_float(u1 & 0xFFFF0000u); \
        float l2 = R[4+s1] - __uint_as_float(u2 & 0xFFFF0000u); \
        float l3 = R[6+s1] - __uint_as_float(u3 & 0xFFFF0000u); \
        u32x2_t hi, lo; \
        hi[0] = pack_hi(u1, u0); hi[1] = pack_hi(u3, u2); \
        lo[0] = pack_hi(__float_as_uint(l1), __float_as_uint(l0)); \
        lo[1] = pack_hi(__float_as_uint(l3), __float_as_uint(l2)); \
        int off = (2 * qp + s1) * LDT + 4 * kq8; \
        *(u32x2_t*)&(DSTH)[off] = hi; \
        *(u32x2_t*)&(DSTL)[off] = lo; } }

#define RELAYC(K0, R) { \
    if (wok) { \
        _Pragma("unroll") \
        for (int j = 0; j < 4; ++j) \
            wscd[(size_t)((K0) + 4 * kq8 + j) * 184 + wsCol] = \
                pack_hi(__float_as_uint(R[2*j+1]), __float_as_uint(R[2*j+0])); } }

#define FRAGMFMA() { \
    bf16x8_t Bhi = *(const bf16x8_t*)&sShi[(16 * wv + ll) * LDT + 8 * lg]; \
    bf16x8_t Blo = *(const bf16x8_t*)&sSlo[(16 * wv + ll) * LDT + 8 * lg]; \
    _Pragma("unroll") \
    for (int mt = 0; mt < 6; ++mt) { \
        bf16x8_t Ahi = *(const bf16x8_t*)&sQhi[(16 * mt + ll) * LDT + 8 * lg]; \
        bf16x8_t Alo = *(const bf16x8_t*)&sQlo[(16 * mt + ll) * LDT + 8 * lg]; \
        acc[mt] = __builtin_amdgcn_mfma_f32_16x16x32_bf16(Ahi, Bhi, acc[mt], 0, 0, 0); \
        acc[mt] = __builtin_amdgcn_mfma_f32_16x16x32_bf16(Ahi, Blo, acc[mt], 0, 0, 0); \
        acc[mt] = __builtin_amdgcn_mfma_f32_16x16x32_bf16(Alo, Bhi, acc[mt], 0, 0, 0); } }

    LOADQ(0, RQa); LOADC(0, RCa);
    for (int k0 = 0; k0 < NDF; k0 += 64) {
        STORE2(RQa, sQhi, sQlo); STORE2(RCa, sShi, sSlo); RELAYC(k0, RCa);
        block_sync_lds();
        if (k0 + 32 < NDF) { LOADQ(k0 + 32, RQb); LOADC(k0 + 32, RCb); }
        __builtin_amdgcn_sched_barrier(0);   // PIN: prefetch issues BEFORE MFMA phase
        FRAGMFMA();
        block_sync_lds();
        STORE2(RQb, sQhi, sQlo); STORE2(RCb, sShi, sSlo); RELAYC(k0 + 32, RCb);
        block_sync_lds();
        if (k0 + 64 < NDF) { LOADQ(k0 + 64, RQa); LOADC(k0 + 64, RCa); }
        __builtin_amdgcn_sched_barrier(0);   // PIN
        FRAGMFMA();
        block_sync_lds();
    }
#undef LOADQ
#undef LOADC
#undef STORE2
#undef RELAYC
#undef FRAGMFMA

    // softmax over q (per s-col), fold *4; D layout: col(s)=ll, row(q)=16mt+4lg+r
    {
        float m = -3.0e38f;
#pragma unroll
        for (int mt = 0; mt < 6; ++mt)
#pragma unroll
            for (int r = 0; r < 4; ++r) m = fmaxf(m, acc[mt][r]);
        m = fmaxf(m, __shfl_xor(m, 16));
        m = fmaxf(m, __shfl_xor(m, 32));
        float sum = 0.0f;
#pragma unroll
        for (int mt = 0; mt < 6; ++mt)
#pragma unroll
            for (int r = 0; r < 4; ++r) {
                float e = __expf(acc[mt][r] - m);
                acc[mt][r] = e;
                sum += e;
            }
        sum += __shfl_xor(sum, 16);
        sum += __shfl_xor(sum, 32);
        float inv = 4.0f / sum;     // fold TEMP1
#pragma unroll
        for (int mt = 0; mt < 6; ++mt)
#pragma unroll
            for (int r = 0; r < 4; ++r) acc[mt][r] *= inv;
    }

    const int sOut = s0 + 16 * wv + ll;
    if constexpr (MODE >= 1) {
        unsigned short* wr = WsLog + (size_t)b * NQ * WSROW;
        if (sOut < NS) {
#pragma unroll
            for (int mt = 0; mt < 6; ++mt)
#pragma unroll
                for (int r = 0; r < 4; ++r) {
                    int q = 16 * mt + 4 * lg + r;
                    wr[q * WSROW + sOut] = f2bf(acc[mt][r]);
                }
        }
    } else {
        float* aout = AoutF + (size_t)b * NQ * NS;
        if (sOut < NS) {
#pragma unroll
            for (int mt = 0; mt < 6; ++mt)
#pragma unroll
                for (int r = 0; r < 4; ++r) {
                    int q = 16 * mt + 4 * lg + r;
                    aout[(size_t)q * NS + sOut] = acc[mt][r];
                }
        }
    }
}

// ================= K15 (fallback only): in-place softmax over s =================
__global__ __launch_bounds__(256) void k15_softmaxs(float* __restrict__ Aout)
{
    const int b = blockIdx.x;
    const int q = blockIdx.y * 4 + (threadIdx.x >> 6);
    const int lane = threadIdx.x & 63;
    float* __restrict__ row = Aout + ((size_t)b * NQ + q) * NS;
    const int c0 = 6 * lane;

    float v[6];
#pragma unroll
    for (int i = 0; i < 6; ++i) v[i] = (c0 + i < NS) ? row[c0 + i] : -INFINITY;
    float m = v[0];
#pragma unroll
    for (int i = 1; i < 6; ++i) m = fmaxf(m, v[i]);
#pragma unroll
    for (int o = 1; o < 64; o <<= 1) m = fmaxf(m, __shfl_xor(m, o));
    float e[6], sum = 0.0f;
#pragma unroll
    for (int i = 0; i < 6; ++i) { e[i] = __expf(v[i] - m); sum += e[i]; }
#pragma unroll
    for (int o = 1; o < 64; o <<= 1) sum += __shfl_xor(sum, o);
    float inv = 1.0f / sum;
#pragma unroll
    for (int i = 0; i < 6; ++i) if (c0 + i < NS) row[c0 + i] = e[i] * inv;
}

// ================= K2: [fused softmax-s +] GEMM2 =================
// grid NB*4 (batch, d-quarter of 192), 512 thr = 8 waves (dw 0..3 x qw 0..1).
// MODE 0: attn fp32 from Aout, ctx fp32.  MODE 1: logits from ws, ctx fp32.
// MODE 2: logits from ws, ctx bf16 from ws (relay).
template<int MODE>
__global__ __launch_bounds__(512, 4) void k2_gemm2(
    const float* __restrict__ Cg, const unsigned short* __restrict__ WsLog,
    const unsigned short* __restrict__ WsCtx,
    const float* __restrict__ AttnF, float* __restrict__ Wout, float* __restrict__ AoutF)
{
    extern __shared__ char smem2[];
    unsigned short* sP = (unsigned short*)smem2;      // [96][LDP]
    unsigned* sPd = (unsigned*)smem2;                 // dword view, stride 196
    float* sMax = (float*)(smem2 + NQ * LDP * 2);     // [96]
    float* sInv = sMax + NQ;                          // [96]

    const int b = blockIdx.x >> 2;
    const int quarter = blockIdx.x & 3;
    const int tid = threadIdx.x;
    const int wv = tid >> 6;
    const int lane = tid & 63;
    const int ll = lane & 15;
    const int lg = lane >> 4;

    if constexpr (MODE >= 1) {
        // stage raw bf16 logits2 from ws; elems >=361 are garbage (masked below)
        const unsigned* __restrict__ wsd = (const unsigned*)(WsLog + (size_t)b * NQ * WSROW);
        for (int i = tid; i < NQ * 184; i += 512) {
            int r = i / 184, c = i - r * 184;
            sPd[r * 196 + c] = wsd[i];
        }
        for (int i = tid; i < NQ * 12; i += 512) {     // zero pad dwords 184..195
            int r = i / 12, c = i - r * 12;
            sPd[r * 196 + 184 + c] = 0;
        }
        __syncthreads();

        const int l32 = tid & 31;
        const int rbase = tid >> 5;    // 0..15
        // ---- max pass (per q-row over s) ----
#pragma unroll
        for (int pass = 0; pass < 6; ++pass) {
            int row = pass * 16 + rbase;
            float m = -3.0e38f;
#pragma unroll
            for (int j = 0; j < 6; ++j) {
                int dw = l32 + 32 * j;
                if (dw < 184) {
                    unsigned u = sPd[row * 196 + dw];
                    float v0 = bf2f((unsigned short)(u & 0xFFFFu));
                    float v1 = bf2f((unsigned short)(u >> 16));
                    if (2 * dw < NS) m = fmaxf(m, v0);
                    if (2 * dw + 1 < NS) m = fmaxf(m, v1);
                }
            }
#pragma unroll
            for (int o = 1; o < 32; o <<= 1) m = fmaxf(m, __shfl_xor(m, o));
            if (l32 == 0) sMax[row] = m;
        }
        __syncthreads();
        // ---- exp pass: store unnormalized exp as bf16; row sums ----
#pragma unroll
        for (int pass = 0; pass < 6; ++pass) {
            int row = pass * 16 + rbase;
            float m = sMax[row];
            float sum = 0.0f;
#pragma unroll
            for (int j = 0; j < 6; ++j) {
                int dw = l32 + 32 * j;
                if (dw < 184) {
                    unsigned u = sPd[row * 196 + dw];
                    float v0 = bf2f((unsigned short)(u & 0xFFFFu));
                    float v1 = bf2f((unsigned short)(u >> 16));
                    float e0 = (2 * dw < NS) ? __expf(v0 - m) : 0.0f;
                    float e1 = (2 * dw + 1 < NS) ? __expf(v1 - m) : 0.0f;
                    sum += e0 + e1;
                    sPd[row * 196 + dw] = ((unsigned)f2bf(e1) << 16) | (unsigned)f2bf(e0);
                }
            }
#pragma unroll
            for (int o = 1; o < 32; o <<= 1) sum += __shfl_xor(sum, o);
            if (l32 == 0) sInv[row] = sum;
        }
        __syncthreads();
        if (tid < NQ) sInv[tid] = 1.0f / sInv[tid];
        __syncthreads();
        if (quarter == 0) {   // write attn_map once per batch
            float* aout = AoutF + (size_t)b * NQ * NS;
            for (int i = tid; i < NQ * NS; i += 512) {
                int q = i / NS, s = i - q * NS;
                aout[i] = bf2f(sP[q * LDP + s]) * sInv[q];
            }
        }
    } else {
        // stage softmaxed fp32 attn -> bf16
        const float* __restrict__ attn = AttnF + (size_t)b * NQ * NS;
        for (int i = tid; i < NQ * 181; i += 512) {
            int row = i / 181, p = i - row * 181;
            float x0 = attn[row * NS + 2 * p];
            float x1 = (p < 180) ? attn[row * NS + 2 * p + 1] : 0.0f;
            sPd[row * 196 + p] = pack_hi(__float_as_uint(x1), __float_as_uint(x0));
        }
        for (int i = tid; i < NQ * 15; i += 512) {
            int row = i / 15, p = i - row * 15;
            sPd[row * 196 + 181 + p] = 0;
        }
        __syncthreads();
    }

    // ---- GEMM2 main loop: A = ctx rows, B = sP ----
    f32x4_t acc[3][3];
#pragma unroll
    for (int i = 0; i < 3; ++i)
#pragma unroll
        for (int j = 0; j < 3; ++j) acc[i][j] = (f32x4_t)0.0f;

    const int dw = wv >> 1, qw = wv & 1;
    const float* __restrict__ cq = Cg + (size_t)b * NDF * NS + (size_t)(quarter * 192) * NS;
    const unsigned short* __restrict__ cb =
        (MODE == 2) ? (WsCtx + ((size_t)b * NDF + quarter * 192) * CSROW) : nullptr;

#pragma unroll
    for (int c = 0; c < 12; ++c) {
        bf16x8_t Bf[3];
#pragma unroll
        for (int nt = 0; nt < 3; ++nt) {
            int row = 16 * (3 * qw + nt) + ll;
            Bf[nt] = *(const bf16x8_t*)&sP[row * LDP + 32 * c + 8 * lg];
        }
#pragma unroll
        for (int i = 0; i < 3; ++i) {
            int d = 16 * (3 * dw + i) + ll;
            bf16x8_t Af;
            if constexpr (MODE == 2) {
                if (c < 11 || lg < 2) {
                    Af = *(const bf16x8_t*)&cb[(size_t)d * CSROW + 32 * c + 8 * lg];
                } else {
                    Af = (bf16x8_t)0;   // s in [368,384): beyond padded row
                }
            } else {
                const float* ap = cq + (size_t)d * NS + 32 * c + 8 * lg;
                u32x4_t u;
                if (c < 11) {
                    f32x4u_t a0 = *(const f32x4u_t*)ap;
                    f32x4u_t a1 = *(const f32x4u_t*)(ap + 4);
                    u[0] = pack_hi(__float_as_uint(a0[1]), __float_as_uint(a0[0]));
                    u[1] = pack_hi(__float_as_uint(a0[3]), __float_as_uint(a0[2]));
                    u[2] = pack_hi(__float_as_uint(a1[1]), __float_as_uint(a1[0]));
                    u[3] = pack_hi(__float_as_uint(a1[3]), __float_as_uint(a1[2]));
                } else {
                    float t[8];
#pragma unroll
                    for (int e = 0; e < 8; ++e) {
                        int s = 352 + 8 * lg + e;
                        t[e] = (s < NS) ? ap[e] : 0.0f;
                    }
                    u[0] = pack_hi(__float_as_uint(t[1]), __float_as_uint(t[0]));
                    u[1] = pack_hi(__float_as_uint(t[3]), __float_as_uint(t[2]));
                    u[2] = pack_hi(__float_as_uint(t[5]), __float_as_uint(t[4]));
                    u[3] = pack_hi(__float_as_uint(t[7]), __float_as_uint(t[6]));
                }
                Af = __builtin_bit_cast(bf16x8_t, u);
            }
#pragma unroll
            for (int nt = 0; nt < 3; ++nt)
                acc[i][nt] = __builtin_amdgcn_mfma_f32_16x16x32_bf16(Af, Bf[nt], acc[i][nt], 0, 0, 0);
        }
    }

    float* wout = Wout + (size_t)b * NDF * NQ;
    float invq[3];
#pragma unroll
    for (int nt = 0; nt < 3; ++nt) {
        if constexpr (MODE >= 1) invq[nt] = sInv[16 * (3 * qw + nt) + ll];
        else invq[nt] = 1.0f;
    }
#pragma unroll
    for (int i = 0; i < 3; ++i)
#pragma unroll
        for (int nt = 0; nt < 3; ++nt)
#pragma unroll
            for (int r = 0; r < 4; ++r) {
                int d = quarter * 192 + 16 * (3 * dw + i) + 4 * lg + r;
                int q = 16 * (3 * qw + nt) + ll;
                wout[(size_t)d * NQ + q] = acc[i][nt][r] * invq[nt];
            }
}

extern "C" void kernel_launch(void* const* d_in, const int* in_sizes, int n_in,
                              void* d_out, int out_size, void* d_ws, size_t ws_size,
                              hipStream_t stream) {
    const float* Qg = (const float*)d_in[0];
    const float* Cg = (const float*)d_in[1];
    float* Wout = (float*)d_out;
    float* Aout = Wout + (size_t)NB * NDF * NQ;   // outputs: weighted_context, attn_map

    const int smem2 = NQ * LDP * 2 + NQ * 8;      // 76032 B

    if (ws_size >= WS_FULL_BYTES) {
        unsigned short* wsLog = (unsigned short*)d_ws;
        unsigned* wsCtxD = (unsigned*)((char*)d_ws + WS_LOG_BYTES);
        k1_gemm1_softmaxq<2><<<dim3(NB * 4), dim3(384), 0, stream>>>(Qg, Cg, wsLog, wsCtxD, nullptr);
        (void)hipFuncSetAttribute((const void*)k2_gemm2<2>,
                                  hipFuncAttributeMaxDynamicSharedMemorySize, smem2);
        k2_gemm2<2><<<dim3(NB * 4), dim3(512), smem2, stream>>>(
            Cg, wsLog, (const unsigned short*)wsCtxD, nullptr, Wout, Aout);
    } else if (ws_size >= WS_LOG_BYTES) {
        unsigned short* wsLog = (unsigned short*)d_ws;
        k1_gemm1_softmaxq<1><<<dim3(NB * 4), dim3(384), 0, stream>>>(Qg, Cg, wsLog, nullptr, nullptr);
        (void)hipFuncSetAttribute((const void*)k2_gemm2<1>,
                                  hipFuncAttributeMaxDynamicSharedMemorySize, smem2);
        k2_gemm2<1><<<dim3(NB * 4), dim3(512), smem2, stream>>>(
            Cg, wsLog, nullptr, nullptr, Wout, Aout);
    } else {
        k1_gemm1_softmaxq<0><<<dim3(NB * 4), dim3(384), 0, stream>>>(Qg, Cg, nullptr, nullptr, Aout);
        k15_softmaxs<<<dim3(NB, 24), dim3(256), 0, stream>>>(Aout);
        (void)hipFuncSetAttribute((const void*)k2_gemm2<0>,
                                  hipFuncAttributeMaxDynamicSharedMemorySize, smem2);
        k2_gemm2<0><<<dim3(NB * 4), dim3(512), smem2, stream>>>(
            Cg, nullptr, nullptr, Aout, Wout, Aout);
    }
}

// Round 9
// 231.151 us; speedup vs baseline: 1.2361x; 1.2361x over previous
//
#include <hip/hip_runtime.h>

// Problem constants
#define NB 256
#define NDF 768
#define NQ 96
#define NS 361
#define LDT 40        // K1 staging stride (bf16 elems): 80B rows, 16B-aligned b128 frags
#define LDP 392       // K2 attn LDS stride (bf16 elems): 784B rows, 16B-aligned
#define WSROW 368     // ws logits row stride (bf16 elems): 184 dwords, 16B-aligned
#define CSROW 368     // ws ctx row stride (bf16 elems): 184 dwords, 16B-aligned
#define WS_LOG_BYTES ((size_t)NB * NQ * WSROW * 2)
#define WS_CTX_BYTES ((size_t)NB * NDF * CSROW * 2)
#define WS_FULL_BYTES (WS_LOG_BYTES + WS_CTX_BYTES)

typedef short bf16x8_t __attribute__((ext_vector_type(8)));
typedef float f32x4_t __attribute__((ext_vector_type(4)));
typedef float f32x4u_t __attribute__((ext_vector_type(4), aligned(4)));
typedef float f32x2u_t __attribute__((ext_vector_type(2), aligned(4)));
typedef unsigned int u32x2_t __attribute__((ext_vector_type(2)));
typedef unsigned int u32x4_t __attribute__((ext_vector_type(4)));

// [b.hi16 | a.hi16] -> one dword (1 v_perm_b32); trunc-to-bf16 pack
__device__ __forceinline__ unsigned pack_hi(unsigned b_, unsigned a_) {
    return __builtin_amdgcn_perm(b_, a_, 0x07060302u);
}
__device__ __forceinline__ unsigned short f2bf(float x) {   // RNE
    unsigned u = __float_as_uint(x);
    u += 0x7FFFu + ((u >> 16) & 1u);
    return (unsigned short)(u >> 16);
}
__device__ __forceinline__ float bf2f(unsigned short h) {
    return __uint_as_float(((unsigned)h) << 16);
}

// LDS-only barrier: orders LDS ops (lgkmcnt) but does NOT drain vmcnt.
__device__ __forceinline__ void block_sync_lds() {
    __builtin_amdgcn_sched_barrier(0);
    asm volatile("s_waitcnt lgkmcnt(0)" ::: "memory");
    __builtin_amdgcn_sched_barrier(0);
    __builtin_amdgcn_s_barrier();
    __builtin_amdgcn_sched_barrier(0);
}

// ================= K1: GEMM1 (split-bf16) + softmax over q =================
// grid NB*2 (batch, s-half of 192), 384 thr = 6 waves; wave: 2 s-tiles x 6 q-tiles.
// 3-buffer prefetch rotation (issue distance = 2 chunks): each global load gets
// ~2 full stage+MFMA phases to complete, and load bursts overlap continuously
// (r7's 1-deep prefetch left HBM idle between phases -> 2.5 TB/s duty).
// MODE 0: softmaxq*4 fp32 -> Aout.  MODE 1: bf16 logits2 -> ws.
// MODE 2: MODE1 + relay ctx bf16 [d][s] -> ws (coalesced dword stores).
template<int MODE>
__global__ __launch_bounds__(384, 3) void k1_gemm1_softmaxq(
    const float* __restrict__ Qg, const float* __restrict__ Cg,
    unsigned short* __restrict__ WsLog, unsigned* __restrict__ WsCtxD,
    float* __restrict__ AoutF)
{
    __shared__ unsigned short sQhi[NQ * LDT];
    __shared__ unsigned short sQlo[NQ * LDT];
    __shared__ unsigned short sShi[192 * LDT];
    __shared__ unsigned short sSlo[192 * LDT];

    const int b = blockIdx.x >> 1;
    const int h = blockIdx.x & 1;
    const int tid = threadIdx.x;
    const int wv = tid >> 6;
    const int lane = tid & 63;
    const int ll = lane & 15;
    const int lg = lane >> 4;
    const int s0 = 192 * h;
    // Q staging: quad (4 k-rows, 1 q); thread does quads kqQ and kqQ+4
    const int qq  = tid % NQ;
    const int kqQ = tid / NQ;          // 0..3
    // C staging: thread owns kq in {kqb, kqb+4}, s in {s0+2sp, s0+2sp+1}
    const int sp  = tid % 96;
    const int kqb = tid / 96;          // 0..3
    const int sA0 = s0 + 2 * sp;
    const bool ok0 = (sA0 < NS);
    const bool ok1 = (sA0 + 1 < NS);
    const int wsCol = 96 * h + sp;     // ctx-ws dword column
    const bool wok = (MODE == 2) && (wsCol < 184);

    const float* __restrict__ qg = Qg + (size_t)b * NDF * NQ;   // [768][96]
    const float* __restrict__ cg = Cg + (size_t)b * NDF * NS;   // [768][361]
    unsigned* __restrict__ wscd = (MODE == 2) ? (WsCtxD + (size_t)b * NDF * 184) : nullptr;

    f32x4_t acc[6][2];
#pragma unroll
    for (int i = 0; i < 6; ++i)
#pragma unroll
        for (int j = 0; j < 2; ++j) acc[i][j] = (f32x4_t)0.0f;

    float RQa[8], RQb[8], RQc[8];
    float RCa[16], RCb[16], RCc[16];   // [k2][j][s01] flattened: (k2*4+j)*2+s01

#define LOADQ(K0, R) { \
    const float* p = qg + ((K0) + 4 * kqQ) * NQ + qq; \
    R[0] = p[0]; R[1] = p[NQ]; R[2] = p[2 * NQ]; R[3] = p[3 * NQ]; \
    const float* p2 = p + 16 * NQ; \
    R[4] = p2[0]; R[5] = p2[NQ]; R[6] = p2[2 * NQ]; R[7] = p2[3 * NQ]; }

#define LOADC(K0, R) { \
    _Pragma("unroll") \
    for (int k2 = 0; k2 < 2; ++k2) { \
        const float* p = cg + ((K0) + 4 * (kqb + 4 * k2)) * NS; \
        _Pragma("unroll") \
        for (int j = 0; j < 4; ++j) { \
            const float* pj = p + j * NS + sA0; \
            f32x2u_t v; \
            if (ok1) { v = *(const f32x2u_t*)pj; } \
            else { v[0] = ok0 ? pj[0] : 0.0f; v[1] = 0.0f; } \
            R[(k2 * 4 + j) * 2 + 0] = v[0]; \
            R[(k2 * 4 + j) * 2 + 1] = v[1]; } } }

#define STOREQ(R) { \
    _Pragma("unroll") \
    for (int t = 0; t < 2; ++t) { \
        unsigned u0 = __float_as_uint(R[4*t+0]), u1 = __float_as_uint(R[4*t+1]); \
        unsigned u2 = __float_as_uint(R[4*t+2]), u3 = __float_as_uint(R[4*t+3]); \
        float l0 = R[4*t+0] - __uint_as_float(u0 & 0xFFFF0000u); \
        float l1 = R[4*t+1] - __uint_as_float(u1 & 0xFFFF0000u); \
        float l2 = R[4*t+2] - __uint_as_float(u2 & 0xFFFF0000u); \
        float l3 = R[4*t+3] - __uint_as_float(u3 & 0xFFFF0000u); \
        u32x2_t hi, lo; \
        hi[0] = pack_hi(u1, u0); hi[1] = pack_hi(u3, u2); \
        lo[0] = pack_hi(__float_as_uint(l1), __float_as_uint(l0)); \
        lo[1] = pack_hi(__float_as_uint(l3), __float_as_uint(l2)); \
        int off = qq * LDT + 4 * (kqQ + 4 * t); \
        *(u32x2_t*)&sQhi[off] = hi; \
        *(u32x2_t*)&sQlo[off] = lo; } }

#define STOREC(K0, R) { \
    _Pragma("unroll") \
    for (int k2 = 0; k2 < 2; ++k2) { \
        const int kq = kqb + 4 * k2; \
        unsigned u[4][2]; float l[4][2]; \
        _Pragma("unroll") \
        for (int j = 0; j < 4; ++j) { \
            _Pragma("unroll") \
            for (int s1 = 0; s1 < 2; ++s1) { \
                float x = R[(k2 * 4 + j) * 2 + s1]; \
                u[j][s1] = __float_as_uint(x); \
                l[j][s1] = x - __uint_as_float(u[j][s1] & 0xFFFF0000u); } } \
        _Pragma("unroll") \
        for (int s1 = 0; s1 < 2; ++s1) { \
            u32x2_t hi, lo; \
            hi[0] = pack_hi(u[1][s1], u[0][s1]); \
            hi[1] = pack_hi(u[3][s1], u[2][s1]); \
            lo[0] = pack_hi(__float_as_uint(l[1][s1]), __float_as_uint(l[0][s1])); \
            lo[1] = pack_hi(__float_as_uint(l[3][s1]), __float_as_uint(l[2][s1])); \
            int off = (2 * sp + s1) * LDT + 4 * kq; \
            *(u32x2_t*)&sShi[off] = hi; \
            *(u32x2_t*)&sSlo[off] = lo; } \
        if (wok) { \
            _Pragma("unroll") \
            for (int j = 0; j < 4; ++j) \
                wscd[(size_t)((K0) + 4 * kq + j) * 184 + wsCol] = pack_hi(u[j][1], u[j][0]); } } }

#define FRAGMFMA() { \
    bf16x8_t Bhi[2], Blo[2]; \
    _Pragma("unroll") \
    for (int nt = 0; nt < 2; ++nt) { \
        int row = 32 * wv + 16 * nt + ll; \
        Bhi[nt] = *(const bf16x8_t*)&sShi[row * LDT + 8 * lg]; \
        Blo[nt] = *(const bf16x8_t*)&sSlo[row * LDT + 8 * lg]; } \
    _Pragma("unroll") \
    for (int mt = 0; mt < 6; ++mt) { \
        int row = 16 * mt + ll; \
        bf16x8_t Ahi = *(const bf16x8_t*)&sQhi[row * LDT + 8 * lg]; \
        bf16x8_t Alo = *(const bf16x8_t*)&sQlo[row * LDT + 8 * lg]; \
        _Pragma("unroll") \
        for (int nt = 0; nt < 2; ++nt) { \
            acc[mt][nt] = __builtin_amdgcn_mfma_f32_16x16x32_bf16(Ahi, Bhi[nt], acc[mt][nt], 0, 0, 0); \
            acc[mt][nt] = __builtin_amdgcn_mfma_f32_16x16x32_bf16(Ahi, Blo[nt], acc[mt][nt], 0, 0, 0); \
            acc[mt][nt] = __builtin_amdgcn_mfma_f32_16x16x32_bf16(Alo, Bhi[nt], acc[mt][nt], 0, 0, 0); } } }

// One pipeline phase: stage set SR (chunk KS), then prefetch chunk KL into LR.
#define PHASE(KS, SRQ, SRC, KL, LRQ, LRC) { \
    STOREQ(SRQ); STOREC(KS, SRC); \
    block_sync_lds(); \
    if ((KL) < NDF) { LOADQ(KL, LRQ); LOADC(KL, LRC); } \
    __builtin_amdgcn_sched_barrier(0); \
    FRAGMFMA(); \
    block_sync_lds(); }

    LOADQ(0, RQa); LOADC(0, RCa);
    LOADQ(32, RQb); LOADC(32, RCb);
    for (int k0 = 0; k0 < NDF; k0 += 96) {
        PHASE(k0,      RQa, RCa, k0 + 64,  RQc, RCc);
        PHASE(k0 + 32, RQb, RCb, k0 + 96,  RQa, RCa);
        PHASE(k0 + 64, RQc, RCc, k0 + 128, RQb, RCb);
    }
#undef LOADQ
#undef LOADC
#undef STOREQ
#undef STOREC
#undef FRAGMFMA
#undef PHASE

    // softmax over q (per s-col), fold *4; D layout: col(s)=ll, row(q)=16mt+4lg+r
#pragma unroll
    for (int nt = 0; nt < 2; ++nt) {
        float m = -3.0e38f;
#pragma unroll
        for (int mt = 0; mt < 6; ++mt)
#pragma unroll
            for (int r = 0; r < 4; ++r) m = fmaxf(m, acc[mt][nt][r]);
        m = fmaxf(m, __shfl_xor(m, 16));
        m = fmaxf(m, __shfl_xor(m, 32));
        float sum = 0.0f;
#pragma unroll
        for (int mt = 0; mt < 6; ++mt)
#pragma unroll
            for (int r = 0; r < 4; ++r) {
                float e = __expf(acc[mt][nt][r] - m);
                acc[mt][nt][r] = e;
                sum += e;
            }
        sum += __shfl_xor(sum, 16);
        sum += __shfl_xor(sum, 32);
        float inv = 4.0f / sum;     // fold TEMP1
#pragma unroll
        for (int mt = 0; mt < 6; ++mt)
#pragma unroll
            for (int r = 0; r < 4; ++r) acc[mt][nt][r] *= inv;
    }

    if constexpr (MODE >= 1) {
        unsigned short* wr = WsLog + (size_t)b * NQ * WSROW;
#pragma unroll
        for (int mt = 0; mt < 6; ++mt)
#pragma unroll
            for (int nt = 0; nt < 2; ++nt)
#pragma unroll
                for (int r = 0; r < 4; ++r) {
                    int q = 16 * mt + 4 * lg + r;
                    int s = s0 + 32 * wv + 16 * nt + ll;
                    if (s < NS) wr[q * WSROW + s] = f2bf(acc[mt][nt][r]);
                }
    } else {
        float* aout = AoutF + (size_t)b * NQ * NS;
#pragma unroll
        for (int mt = 0; mt < 6; ++mt)
#pragma unroll
            for (int nt = 0; nt < 2; ++nt)
#pragma unroll
                for (int r = 0; r < 4; ++r) {
                    int q = 16 * mt + 4 * lg + r;
                    int s = s0 + 32 * wv + 16 * nt + ll;
                    if (s < NS) aout[(size_t)q * NS + s] = acc[mt][nt][r];
                }
    }
}

// ================= K15 (fallback only): in-place softmax over s =================
__global__ __launch_bounds__(256) void k15_softmaxs(float* __restrict__ Aout)
{
    const int b = blockIdx.x;
    const int q = blockIdx.y * 4 + (threadIdx.x >> 6);
    const int lane = threadIdx.x & 63;
    float* __restrict__ row = Aout + ((size_t)b * NQ + q) * NS;
    const int c0 = 6 * lane;

    float v[6];
#pragma unroll
    for (int i = 0; i < 6; ++i) v[i] = (c0 + i < NS) ? row[c0 + i] : -INFINITY;
    float m = v[0];
#pragma unroll
    for (int i = 1; i < 6; ++i) m = fmaxf(m, v[i]);
#pragma unroll
    for (int o = 1; o < 64; o <<= 1) m = fmaxf(m, __shfl_xor(m, o));
    float e[6], sum = 0.0f;
#pragma unroll
    for (int i = 0; i < 6; ++i) { e[i] = __expf(v[i] - m); sum += e[i]; }
#pragma unroll
    for (int o = 1; o < 64; o <<= 1) sum += __shfl_xor(sum, o);
    float inv = 1.0f / sum;
#pragma unroll
    for (int i = 0; i < 6; ++i) if (c0 + i < NS) row[c0 + i] = e[i] * inv;
}

// ================= K2: [fused softmax-s +] GEMM2 =================
// grid NB*4 (batch, d-quarter of 192), 512 thr = 8 waves (dw 0..3 x qw 0..1).
// MODE 0: attn fp32 from Aout, ctx fp32.  MODE 1: logits from ws, ctx fp32.
// MODE 2: logits from ws, ctx bf16 from ws (relay).
template<int MODE>
__global__ __launch_bounds__(512, 4) void k2_gemm2(
    const float* __restrict__ Cg, const unsigned short* __restrict__ WsLog,
    const unsigned short* __restrict__ WsCtx,
    const float* __restrict__ AttnF, float* __restrict__ Wout, float* __restrict__ AoutF)
{
    extern __shared__ char smem2[];
    unsigned short* sP = (unsigned short*)smem2;      // [96][LDP]
    unsigned* sPd = (unsigned*)smem2;                 // dword view, stride 196
    float* sMax = (float*)(smem2 + NQ * LDP * 2);     // [96]
    float* sInv = sMax + NQ;                          // [96]

    const int b = blockIdx.x >> 2;
    const int quarter = blockIdx.x & 3;
    const int tid = threadIdx.x;
    const int wv = tid >> 6;
    const int lane = tid & 63;
    const int ll = lane & 15;
    const int lg = lane >> 4;

    if constexpr (MODE >= 1) {
        // stage raw bf16 logits2 from ws; elems >=361 are garbage (masked below)
        const unsigned* __restrict__ wsd = (const unsigned*)(WsLog + (size_t)b * NQ * WSROW);
        for (int i = tid; i < NQ * 184; i += 512) {
            int r = i / 184, c = i - r * 184;
            sPd[r * 196 + c] = wsd[i];
        }
        for (int i = tid; i < NQ * 12; i += 512) {     // zero pad dwords 184..195
            int r = i / 12, c = i - r * 12;
            sPd[r * 196 + 184 + c] = 0;
        }
        __syncthreads();

        const int l32 = tid & 31;
        const int rbase = tid >> 5;    // 0..15
        // ---- max pass (per q-row over s) ----
#pragma unroll
        for (int pass = 0; pass < 6; ++pass) {
            int row = pass * 16 + rbase;
            float m = -3.0e38f;
#pragma unroll
            for (int j = 0; j < 6; ++j) {
                int dw = l32 + 32 * j;
                if (dw < 184) {
                    unsigned u = sPd[row * 196 + dw];
                    float v0 = bf2f((unsigned short)(u & 0xFFFFu));
                    float v1 = bf2f((unsigned short)(u >> 16));
                    if (2 * dw < NS) m = fmaxf(m, v0);
                    if (2 * dw + 1 < NS) m = fmaxf(m, v1);
                }
            }
#pragma unroll
            for (int o = 1; o < 32; o <<= 1) m = fmaxf(m, __shfl_xor(m, o));
            if (l32 == 0) sMax[row] = m;
        }
        __syncthreads();
        // ---- exp pass: store unnormalized exp as bf16; row sums ----
#pragma unroll
        for (int pass = 0; pass < 6; ++pass) {
            int row = pass * 16 + rbase;
            float m = sMax[row];
            float sum = 0.0f;
#pragma unroll
            for (int j = 0; j < 6; ++j) {
                int dw = l32 + 32 * j;
                if (dw < 184) {
                    unsigned u = sPd[row * 196 + dw];
                    float v0 = bf2f((unsigned short)(u & 0xFFFFu));
                    float v1 = bf2f((unsigned short)(u >> 16));
                    float e0 = (2 * dw < NS) ? __expf(v0 - m) : 0.0f;
                    float e1 = (2 * dw + 1 < NS) ? __expf(v1 - m) : 0.0f;
                    sum += e0 + e1;
                    sPd[row * 196 + dw] = ((unsigned)f2bf(e1) << 16) | (unsigned)f2bf(e0);
                }
            }
#pragma unroll
            for (int o = 1; o < 32; o <<= 1) sum += __shfl_xor(sum, o);
            if (l32 == 0) sInv[row] = sum;
        }
        __syncthreads();
        if (tid < NQ) sInv[tid] = 1.0f / sInv[tid];
        __syncthreads();
        if (quarter == 0) {   // write attn_map once per batch
            float* aout = AoutF + (size_t)b * NQ * NS;
            for (int i = tid; i < NQ * NS; i += 512) {
                int q = i / NS, s = i - q * NS;
                aout[i] = bf2f(sP[q * LDP + s]) * sInv[q];
            }
        }
    } else {
        // stage softmaxed fp32 attn -> bf16
        const float* __restrict__ attn = AttnF + (size_t)b * NQ * NS;
        for (int i = tid; i < NQ * 181; i += 512) {
            int row = i / 181, p = i - row * 181;
            float x0 = attn[row * NS + 2 * p];
            float x1 = (p < 180) ? attn[row * NS + 2 * p + 1] : 0.0f;
            sPd[row * 196 + p] = pack_hi(__float_as_uint(x1), __float_as_uint(x0));
        }
        for (int i = tid; i < NQ * 15; i += 512) {
            int row = i / 15, p = i - row * 15;
            sPd[row * 196 + 181 + p] = 0;
        }
        __syncthreads();
    }

    // ---- GEMM2 main loop: A = ctx rows, B = sP ----
    f32x4_t acc[3][3];
#pragma unroll
    for (int i = 0; i < 3; ++i)
#pragma unroll
        for (int j = 0; j < 3; ++j) acc[i][j] = (f32x4_t)0.0f;

    const int dw = wv >> 1, qw = wv & 1;
    const float* __restrict__ cq = Cg + (size_t)b * NDF * NS + (size_t)(quarter * 192) * NS;
    const unsigned short* __restrict__ cb =
        (MODE == 2) ? (WsCtx + ((size_t)b * NDF + quarter * 192) * CSROW) : nullptr;

#pragma unroll
    for (int c = 0; c < 12; ++c) {
        bf16x8_t Bf[3];
#pragma unroll
        for (int nt = 0; nt < 3; ++nt) {
            int row = 16 * (3 * qw + nt) + ll;
            Bf[nt] = *(const bf16x8_t*)&sP[row * LDP + 32 * c + 8 * lg];
        }
#pragma unroll
        for (int i = 0; i < 3; ++i) {
            int d = 16 * (3 * dw + i) + ll;
            bf16x8_t Af;
            if constexpr (MODE == 2) {
                if (c < 11 || lg < 2) {
                    Af = *(const bf16x8_t*)&cb[(size_t)d * CSROW + 32 * c + 8 * lg];
                } else {
                    Af = (bf16x8_t)0;   // s in [368,384): beyond padded row
                }
            } else {
                const float* ap = cq + (size_t)d * NS + 32 * c + 8 * lg;
                u32x4_t u;
                if (c < 11) {
                    f32x4u_t a0 = *(const f32x4u_t*)ap;
                    f32x4u_t a1 = *(const f32x4u_t*)(ap + 4);
                    u[0] = pack_hi(__float_as_uint(a0[1]), __float_as_uint(a0[0]));
                    u[1] = pack_hi(__float_as_uint(a0[3]), __float_as_uint(a0[2]));
                    u[2] = pack_hi(__float_as_uint(a1[1]), __float_as_uint(a1[0]));
                    u[3] = pack_hi(__float_as_uint(a1[3]), __float_as_uint(a1[2]));
                } else {
                    float t[8];
#pragma unroll
                    for (int e = 0; e < 8; ++e) {
                        int s = 352 + 8 * lg + e;
                        t[e] = (s < NS) ? ap[e] : 0.0f;
                    }
                    u[0] = pack_hi(__float_as_uint(t[1]), __float_as_uint(t[0]));
                    u[1] = pack_hi(__float_as_uint(t[3]), __float_as_uint(t[2]));
                    u[2] = pack_hi(__float_as_uint(t[5]), __float_as_uint(t[4]));
                    u[3] = pack_hi(__float_as_uint(t[7]), __float_as_uint(t[6]));
                }
                Af = __builtin_bit_cast(bf16x8_t, u);
            }
#pragma unroll
            for (int nt = 0; nt < 3; ++nt)
                acc[i][nt] = __builtin_amdgcn_mfma_f32_16x16x32_bf16(Af, Bf[nt], acc[i][nt], 0, 0, 0);
        }
    }

    float* wout = Wout + (size_t)b * NDF * NQ;
    float invq[3];
#pragma unroll
    for (int nt = 0; nt < 3; ++nt) {
        if constexpr (MODE >= 1) invq[nt] = sInv[16 * (3 * qw + nt) + ll];
        else invq[nt] = 1.0f;
    }
#pragma unroll
    for (int i = 0; i < 3; ++i)
#pragma unroll
        for (int nt = 0; nt < 3; ++nt)
#pragma unroll
            for (int r = 0; r < 4; ++r) {
                int d = quarter * 192 + 16 * (3 * dw + i) + 4 * lg + r;
                int q = 16 * (3 * qw + nt) + ll;
                wout[(size_t)d * NQ + q] = acc[i][nt][r] * invq[nt];
            }
}

extern "C" void kernel_launch(void* const* d_in, const int* in_sizes, int n_in,
                              void* d_out, int out_size, void* d_ws, size_t ws_size,
                              hipStream_t stream) {
    const float* Qg = (const float*)d_in[0];
    const float* Cg = (const float*)d_in[1];
    float* Wout = (float*)d_out;
    float* Aout = Wout + (size_t)NB * NDF * NQ;   // outputs: weighted_context, attn_map

    const int smem2 = NQ * LDP * 2 + NQ * 8;      // 76032 B

    if (ws_size >= WS_FULL_BYTES) {
        unsigned short* wsLog = (unsigned short*)d_ws;
        unsigned* wsCtxD = (unsigned*)((char*)d_ws + WS_LOG_BYTES);
        k1_gemm1_softmaxq<2><<<dim3(NB * 2), dim3(384), 0, stream>>>(Qg, Cg, wsLog, wsCtxD, nullptr);
        (void)hipFuncSetAttribute((const void*)k2_gemm2<2>,
                                  hipFuncAttributeMaxDynamicSharedMemorySize, smem2);
        k2_gemm2<2><<<dim3(NB * 4), dim3(512), smem2, stream>>>(
            Cg, wsLog, (const unsigned short*)wsCtxD, nullptr, Wout, Aout);
    } else if (ws_size >= WS_LOG_BYTES) {
        unsigned short* wsLog = (unsigned short*)d_ws;
        k1_gemm1_softmaxq<1><<<dim3(NB * 2), dim3(384), 0, stream>>>(Qg, Cg, wsLog, nullptr, nullptr);
        (void)hipFuncSetAttribute((const void*)k2_gemm2<1>,
                                  hipFuncAttributeMaxDynamicSharedMemorySize, smem2);
        k2_gemm2<1><<<dim3(NB * 4), dim3(512), smem2, stream>>>(
            Cg, wsLog, nullptr, nullptr, Wout, Aout);
    } else {
        k1_gemm1_softmaxq<0><<<dim3(NB * 2), dim3(384), 0, stream>>>(Qg, Cg, nullptr, nullptr, Aout);
        k15_softmaxs<<<dim3(NB, 24), dim3(256), 0, stream>>>(Aout);
        (void)hipFuncSetAttribute((const void*)k2_gemm2<0>,
                                  hipFuncAttributeMaxDynamicSharedMemorySize, smem2);
        k2_gemm2<0><<<dim3(NB * 4), dim3(512), smem2, stream>>>(
            Cg, nullptr, nullptr, Aout, Wout, Aout);
    }
}

// Round 10
// 208.988 us; speedup vs baseline: 1.3672x; 1.1060x over previous
//
#include <hip/hip_runtime.h>

// Problem constants
#define NB 256
#define NDF 768
#define NQ 96
#define NS 361
#define LDT 40        // Q staging stride (bf16 elems): 80B rows; octet writes/reads are bank-balanced
#define LDP 392       // K2 attn LDS stride (bf16 elems): 784B rows, 16B-aligned
#define WSROW 368     // ws logits row stride (bf16 elems): 184 dwords, 16B-aligned
#define WS_LOG_BYTES ((size_t)NB * NQ * WSROW * 2)

typedef short bf16x8_t __attribute__((ext_vector_type(8)));
typedef float f32x4_t __attribute__((ext_vector_type(4)));
typedef float f32x4u_t __attribute__((ext_vector_type(4), aligned(4)));
typedef unsigned int u32x4_t __attribute__((ext_vector_type(4)));

// [b.hi16 | a.hi16] -> one dword (1 v_perm_b32)
__device__ __forceinline__ unsigned pack_hi(unsigned b_, unsigned a_) {
    return __builtin_amdgcn_perm(b_, a_, 0x07060302u);
}
__device__ __forceinline__ unsigned short f2bf(float x) {   // RNE
    unsigned u = __float_as_uint(x);
    u += 0x7FFFu + ((u >> 16) & 1u);
    return (unsigned short)(u >> 16);
}
__device__ __forceinline__ float bf2f(unsigned short h) {
    return __uint_as_float(((unsigned)h) << 16);
}

// split-bf16 convert: 8 fp32 -> hi bf16x8 (trunc) + lo bf16x8 (residual, trunc)
__device__ __forceinline__ void cvt8(const float* x, bf16x8_t& hi, bf16x8_t& lo) {
    unsigned uh[8]; float fl[8];
#pragma unroll
    for (int j = 0; j < 8; ++j) {
        unsigned u = __float_as_uint(x[j]);
        uh[j] = u;
        fl[j] = x[j] - __uint_as_float(u & 0xFFFF0000u);
    }
    u32x4_t h, l;
    h[0] = pack_hi(uh[1], uh[0]); h[1] = pack_hi(uh[3], uh[2]);
    h[2] = pack_hi(uh[5], uh[4]); h[3] = pack_hi(uh[7], uh[6]);
    l[0] = pack_hi(__float_as_uint(fl[1]), __float_as_uint(fl[0]));
    l[1] = pack_hi(__float_as_uint(fl[3]), __float_as_uint(fl[2]));
    l[2] = pack_hi(__float_as_uint(fl[5]), __float_as_uint(fl[4]));
    l[3] = pack_hi(__float_as_uint(fl[7]), __float_as_uint(fl[6]));
    hi = __builtin_bit_cast(bf16x8_t, h);
    lo = __builtin_bit_cast(bf16x8_t, l);
}

// LDS-only barrier: orders LDS ops; global loads (0x20) may cross freely.
__device__ __forceinline__ void block_sync_lds() {
    __builtin_amdgcn_sched_barrier(0x20);
    asm volatile("s_waitcnt lgkmcnt(0)" ::: "memory");
    __builtin_amdgcn_sched_barrier(0x20);
    __builtin_amdgcn_s_barrier();
    __builtin_amdgcn_sched_barrier(0x20);
}

// ================= K1: GEMM1 (split-bf16) + softmax over q =================
// grid NB*2 (batch, s-half of 192), 384 thr = 6 waves; wave: 2 s-tiles x 6 q-tiles.
// ctx B-fragments load DIRECTLY from global (no LDS, no transpose, no barrier dep);
// only Q is LDS-staged (12KB/chunk, double-buffered, conflict-free octet writes,
// one lgkm-only barrier per chunk). XCD-paired swizzle: both halves of a batch
// land on the same XCD so the 2nd Q read is an L2 hit.
// MODE 1: bf16 logits2 -> ws.  MODE 0: softmaxq*4 fp32 -> Aout (fallback).
template<int MODE>
__global__ __launch_bounds__(384, 3) void k1_gemm1_softmaxq(
    const float* __restrict__ Qg, const float* __restrict__ Cg,
    unsigned short* __restrict__ WsLog, float* __restrict__ AoutF)
{
    __shared__ __align__(16) unsigned short sQhi[2][NQ * LDT];
    __shared__ __align__(16) unsigned short sQlo[2][NQ * LDT];

    // XCD-pairing swizzle (grid 512 = 8 xcd * 32 batch-groups * 2 halves)
    const int x = blockIdx.x;
    const int b = (x & 7) * 32 + (x >> 4);
    const int h = (x >> 3) & 1;

    const int tid = threadIdx.x;
    const int wv = tid >> 6;
    const int lane = tid & 63;
    const int ll = lane & 15;
    const int lg = lane >> 4;
    const int s0 = 192 * h;
    // Q staging geometry: thread owns column qq and k-octet koct (96*4 = 384 units)
    const int qq = tid % 96;
    const int koct = tid / 96;         // 0..3
    // B-fragment columns for this lane (clamped; fake s>=NS computes garbage, never written)
    const int sc0 = min(s0 + 32 * wv + ll, NS - 1);
    const int sc1 = min(s0 + 32 * wv + 16 + ll, NS - 1);

    const float* __restrict__ qg = Qg + (size_t)b * NDF * NQ;   // [768][96]
    const float* __restrict__ cg = Cg + (size_t)b * NDF * NS;   // [768][361]

    f32x4_t acc[6][2];
#pragma unroll
    for (int i = 0; i < 6; ++i)
#pragma unroll
        for (int j = 0; j < 2; ++j) acc[i][j] = (f32x4_t)0.0f;

    float rq[8];

#define LOADQ(K0) { \
    _Pragma("unroll") \
    for (int j = 0; j < 8; ++j) \
        rq[j] = qg[((K0) + 8 * koct + j) * NQ + qq]; }

#define STAGEQ(BUF) { \
    bf16x8_t qh, ql; \
    cvt8(rq, qh, ql); \
    *(bf16x8_t*)&sQhi[BUF][qq * LDT + 8 * koct] = qh; \
    *(bf16x8_t*)&sQlo[BUF][qq * LDT + 8 * koct] = ql; }

    LOADQ(0);
    STAGEQ(0);
    block_sync_lds();

    for (int k0 = 0; k0 < NDF; k0 += 32) {
        const int cur = (k0 >> 5) & 1;
        // ctx fragment loads: 16 stride-NS dwords, issued first (vmcnt(8) covers them)
        float c0v[8], c1v[8];
#pragma unroll
        for (int j = 0; j < 8; ++j) c0v[j] = cg[(size_t)(k0 + 8 * lg + j) * NS + sc0];
#pragma unroll
        for (int j = 0; j < 8; ++j) c1v[j] = cg[(size_t)(k0 + 8 * lg + j) * NS + sc1];
        if (k0 + 32 < NDF) LOADQ(k0 + 32);   // Q prefetch: consumed at STAGEQ below
        bf16x8_t B0h, B0l, B1h, B1l;
        cvt8(c0v, B0h, B0l);
        cvt8(c1v, B1h, B1l);
#pragma unroll
        for (int mt = 0; mt < 6; ++mt) {
            bf16x8_t Ah = *(const bf16x8_t*)&sQhi[cur][(16 * mt + ll) * LDT + 8 * lg];
            bf16x8_t Al = *(const bf16x8_t*)&sQlo[cur][(16 * mt + ll) * LDT + 8 * lg];
            acc[mt][0] = __builtin_amdgcn_mfma_f32_16x16x32_bf16(Ah, B0h, acc[mt][0], 0, 0, 0);
            acc[mt][0] = __builtin_amdgcn_mfma_f32_16x16x32_bf16(Ah, B0l, acc[mt][0], 0, 0, 0);
            acc[mt][0] = __builtin_amdgcn_mfma_f32_16x16x32_bf16(Al, B0h, acc[mt][0], 0, 0, 0);
            acc[mt][1] = __builtin_amdgcn_mfma_f32_16x16x32_bf16(Ah, B1h, acc[mt][1], 0, 0, 0);
            acc[mt][1] = __builtin_amdgcn_mfma_f32_16x16x32_bf16(Ah, B1l, acc[mt][1], 0, 0, 0);
            acc[mt][1] = __builtin_amdgcn_mfma_f32_16x16x32_bf16(Al, B1h, acc[mt][1], 0, 0, 0);
        }
        if (k0 + 32 < NDF) STAGEQ(cur ^ 1);
        block_sync_lds();
    }
#undef LOADQ
#undef STAGEQ

    // softmax over q (per s-col), fold *4; D layout: col(s)=ll, row(q)=16mt+4lg+r
#pragma unroll
    for (int nt = 0; nt < 2; ++nt) {
        float m = -3.0e38f;
#pragma unroll
        for (int mt = 0; mt < 6; ++mt)
#pragma unroll
            for (int r = 0; r < 4; ++r) m = fmaxf(m, acc[mt][nt][r]);
        m = fmaxf(m, __shfl_xor(m, 16));
        m = fmaxf(m, __shfl_xor(m, 32));
        float sum = 0.0f;
#pragma unroll
        for (int mt = 0; mt < 6; ++mt)
#pragma unroll
            for (int r = 0; r < 4; ++r) {
                float e = __expf(acc[mt][nt][r] - m);
                acc[mt][nt][r] = e;
                sum += e;
            }
        sum += __shfl_xor(sum, 16);
        sum += __shfl_xor(sum, 32);
        float inv = 4.0f / sum;     // fold TEMP1
#pragma unroll
        for (int mt = 0; mt < 6; ++mt)
#pragma unroll
            for (int r = 0; r < 4; ++r) acc[mt][nt][r] *= inv;
    }

    if constexpr (MODE >= 1) {
        unsigned short* wr = WsLog + (size_t)b * NQ * WSROW;
#pragma unroll
        for (int mt = 0; mt < 6; ++mt)
#pragma unroll
            for (int nt = 0; nt < 2; ++nt)
#pragma unroll
                for (int r = 0; r < 4; ++r) {
                    int q = 16 * mt + 4 * lg + r;
                    int s = s0 + 32 * wv + 16 * nt + ll;
                    if (s < NS) wr[q * WSROW + s] = f2bf(acc[mt][nt][r]);
                }
    } else {
        float* aout = AoutF + (size_t)b * NQ * NS;
#pragma unroll
        for (int mt = 0; mt < 6; ++mt)
#pragma unroll
            for (int nt = 0; nt < 2; ++nt)
#pragma unroll
                for (int r = 0; r < 4; ++r) {
                    int q = 16 * mt + 4 * lg + r;
                    int s = s0 + 32 * wv + 16 * nt + ll;
                    if (s < NS) aout[(size_t)q * NS + s] = acc[mt][nt][r];
                }
    }
}

// ================= K15 (fallback only): in-place softmax over s =================
__global__ __launch_bounds__(256) void k15_softmaxs(float* __restrict__ Aout)
{
    const int b = blockIdx.x;
    const int q = blockIdx.y * 4 + (threadIdx.x >> 6);
    const int lane = threadIdx.x & 63;
    float* __restrict__ row = Aout + ((size_t)b * NQ + q) * NS;
    const int c0 = 6 * lane;

    float v[6];
#pragma unroll
    for (int i = 0; i < 6; ++i) v[i] = (c0 + i < NS) ? row[c0 + i] : -INFINITY;
    float m = v[0];
#pragma unroll
    for (int i = 1; i < 6; ++i) m = fmaxf(m, v[i]);
#pragma unroll
    for (int o = 1; o < 64; o <<= 1) m = fmaxf(m, __shfl_xor(m, o));
    float e[6], sum = 0.0f;
#pragma unroll
    for (int i = 0; i < 6; ++i) { e[i] = __expf(v[i] - m); sum += e[i]; }
#pragma unroll
    for (int o = 1; o < 64; o <<= 1) sum += __shfl_xor(sum, o);
    float inv = 1.0f / sum;
#pragma unroll
    for (int i = 0; i < 6; ++i) if (c0 + i < NS) row[c0 + i] = e[i] * inv;
}

// ================= K2: [fused softmax-s +] GEMM2 =================
// grid NB*4 (batch, d-quarter of 192), 512 thr = 8 waves (dw 0..3 x qw 0..1).
// XCD-paired swizzle: all 4 quarters of a batch share an XCD (ws logits L2 hits).
// FUSED: logits from ws + softmax-s in LDS + attn_map write.  else: attn fp32 from Aout.
template<bool FUSED>
__global__ __launch_bounds__(512, 4) void k2_gemm2(
    const float* __restrict__ Cg, const unsigned short* __restrict__ WsLog,
    const float* __restrict__ AttnF, float* __restrict__ Wout, float* __restrict__ AoutF)
{
    extern __shared__ char smem2[];
    unsigned short* sP = (unsigned short*)smem2;      // [96][LDP]
    unsigned* sPd = (unsigned*)smem2;                 // dword view, stride 196
    float* sMax = (float*)(smem2 + NQ * LDP * 2);     // [96]
    float* sInv = sMax + NQ;                          // [96]

    const int x = blockIdx.x;
    const int b = (x & 7) * 32 + (x >> 5);
    const int quarter = (x >> 3) & 3;
    const int tid = threadIdx.x;
    const int wv = tid >> 6;
    const int lane = tid & 63;
    const int ll = lane & 15;
    const int lg = lane >> 4;

    if constexpr (FUSED) {
        // stage raw bf16 logits2 from ws; elems >=361 are garbage (masked below)
        const unsigned* __restrict__ wsd = (const unsigned*)(WsLog + (size_t)b * NQ * WSROW);
        for (int i = tid; i < NQ * 184; i += 512) {
            int r = i / 184, c = i - r * 184;
            sPd[r * 196 + c] = wsd[i];
        }
        for (int i = tid; i < NQ * 12; i += 512) {     // zero pad dwords 184..195
            int r = i / 12, c = i - r * 12;
            sPd[r * 196 + 184 + c] = 0;
        }
        __syncthreads();

        const int l32 = tid & 31;
        const int rbase = tid >> 5;    // 0..15
        // ---- max pass (per q-row over s) ----
#pragma unroll
        for (int pass = 0; pass < 6; ++pass) {
            int row = pass * 16 + rbase;
            float m = -3.0e38f;
#pragma unroll
            for (int j = 0; j < 6; ++j) {
                int dw = l32 + 32 * j;
                if (dw < 184) {
                    unsigned u = sPd[row * 196 + dw];
                    float v0 = bf2f((unsigned short)(u & 0xFFFFu));
                    float v1 = bf2f((unsigned short)(u >> 16));
                    if (2 * dw < NS) m = fmaxf(m, v0);
                    if (2 * dw + 1 < NS) m = fmaxf(m, v1);
                }
            }
#pragma unroll
            for (int o = 1; o < 32; o <<= 1) m = fmaxf(m, __shfl_xor(m, o));
            if (l32 == 0) sMax[row] = m;
        }
        __syncthreads();
        // ---- exp pass: store unnormalized exp as bf16; row sums ----
#pragma unroll
        for (int pass = 0; pass < 6; ++pass) {
            int row = pass * 16 + rbase;
            float m = sMax[row];
            float sum = 0.0f;
#pragma unroll
            for (int j = 0; j < 6; ++j) {
                int dw = l32 + 32 * j;
                if (dw < 184) {
                    unsigned u = sPd[row * 196 + dw];
                    float v0 = bf2f((unsigned short)(u & 0xFFFFu));
                    float v1 = bf2f((unsigned short)(u >> 16));
                    float e0 = (2 * dw < NS) ? __expf(v0 - m) : 0.0f;
                    float e1 = (2 * dw + 1 < NS) ? __expf(v1 - m) : 0.0f;
                    sum += e0 + e1;
                    sPd[row * 196 + dw] = ((unsigned)f2bf(e1) << 16) | (unsigned)f2bf(e0);
                }
            }
#pragma unroll
            for (int o = 1; o < 32; o <<= 1) sum += __shfl_xor(sum, o);
            if (l32 == 0) sInv[row] = sum;
        }
        __syncthreads();
        if (tid < NQ) sInv[tid] = 1.0f / sInv[tid];
        __syncthreads();
        if (quarter == 0) {   // write attn_map once per batch
            float* aout = AoutF + (size_t)b * NQ * NS;
            for (int i = tid; i < NQ * NS; i += 512) {
                int q = i / NS, s = i - q * NS;
                aout[i] = bf2f(sP[q * LDP + s]) * sInv[q];
            }
        }
    } else {
        // stage softmaxed fp32 attn -> bf16
        const float* __restrict__ attn = AttnF + (size_t)b * NQ * NS;
        for (int i = tid; i < NQ * 181; i += 512) {
            int row = i / 181, p = i - row * 181;
            float x0 = attn[row * NS + 2 * p];
            float x1 = (p < 180) ? attn[row * NS + 2 * p + 1] : 0.0f;
            sPd[row * 196 + p] = pack_hi(__float_as_uint(x1), __float_as_uint(x0));
        }
        for (int i = tid; i < NQ * 15; i += 512) {
            int row = i / 15, p = i - row * 15;
            sPd[row * 196 + 181 + p] = 0;
        }
        __syncthreads();
    }

    // ---- GEMM2 main loop: A = ctx rows (fp32 direct + perm), B = sP ----
    f32x4_t acc[3][3];
#pragma unroll
    for (int i = 0; i < 3; ++i)
#pragma unroll
        for (int j = 0; j < 3; ++j) acc[i][j] = (f32x4_t)0.0f;

    const int dw = wv >> 1, qw = wv & 1;
    const float* __restrict__ cq = Cg + (size_t)b * NDF * NS + (size_t)(quarter * 192) * NS;

#pragma unroll
    for (int c = 0; c < 12; ++c) {
        bf16x8_t Bf[3];
#pragma unroll
        for (int nt = 0; nt < 3; ++nt) {
            int row = 16 * (3 * qw + nt) + ll;
            Bf[nt] = *(const bf16x8_t*)&sP[row * LDP + 32 * c + 8 * lg];
        }
#pragma unroll
        for (int i = 0; i < 3; ++i) {
            int d = 16 * (3 * dw + i) + ll;
            const float* ap = cq + (size_t)d * NS + 32 * c + 8 * lg;
            u32x4_t u;
            if (c < 11) {
                f32x4u_t a0 = *(const f32x4u_t*)ap;
                f32x4u_t a1 = *(const f32x4u_t*)(ap + 4);
                u[0] = pack_hi(__float_as_uint(a0[1]), __float_as_uint(a0[0]));
                u[1] = pack_hi(__float_as_uint(a0[3]), __float_as_uint(a0[2]));
                u[2] = pack_hi(__float_as_uint(a1[1]), __float_as_uint(a1[0]));
                u[3] = pack_hi(__float_as_uint(a1[3]), __float_as_uint(a1[2]));
            } else {
                float t[8];
#pragma unroll
                for (int e = 0; e < 8; ++e) {
                    int s = 352 + 8 * lg + e;
                    t[e] = (s < NS) ? ap[e] : 0.0f;
                }
                u[0] = pack_hi(__float_as_uint(t[1]), __float_as_uint(t[0]));
                u[1] = pack_hi(__float_as_uint(t[3]), __float_as_uint(t[2]));
                u[2] = pack_hi(__float_as_uint(t[5]), __float_as_uint(t[4]));
                u[3] = pack_hi(__float_as_uint(t[7]), __float_as_uint(t[6]));
            }
            bf16x8_t Af = __builtin_bit_cast(bf16x8_t, u);
#pragma unroll
            for (int nt = 0; nt < 3; ++nt)
                acc[i][nt] = __builtin_amdgcn_mfma_f32_16x16x32_bf16(Af, Bf[nt], acc[i][nt], 0, 0, 0);
        }
    }

    float* wout = Wout + (size_t)b * NDF * NQ;
    float invq[3];
#pragma unroll
    for (int nt = 0; nt < 3; ++nt) {
        if constexpr (FUSED) invq[nt] = sInv[16 * (3 * qw + nt) + ll];
        else invq[nt] = 1.0f;
    }
#pragma unroll
    for (int i = 0; i < 3; ++i)
#pragma unroll
        for (int nt = 0; nt < 3; ++nt)
#pragma unroll
            for (int r = 0; r < 4; ++r) {
                int d = quarter * 192 + 16 * (3 * dw + i) + 4 * lg + r;
                int q = 16 * (3 * qw + nt) + ll;
                wout[(size_t)d * NQ + q] = acc[i][nt][r] * invq[nt];
            }
}

extern "C" void kernel_launch(void* const* d_in, const int* in_sizes, int n_in,
                              void* d_out, int out_size, void* d_ws, size_t ws_size,
                              hipStream_t stream) {
    const float* Qg = (const float*)d_in[0];
    const float* Cg = (const float*)d_in[1];
    float* Wout = (float*)d_out;
    float* Aout = Wout + (size_t)NB * NDF * NQ;   // outputs: weighted_context, attn_map

    const int smem2 = NQ * LDP * 2 + NQ * 8;      // 76032 B

    if (ws_size >= WS_LOG_BYTES) {
        unsigned short* wsLog = (unsigned short*)d_ws;
        k1_gemm1_softmaxq<1><<<dim3(NB * 2), dim3(384), 0, stream>>>(Qg, Cg, wsLog, nullptr);
        (void)hipFuncSetAttribute((const void*)k2_gemm2<true>,
                                  hipFuncAttributeMaxDynamicSharedMemorySize, smem2);
        k2_gemm2<true><<<dim3(NB * 4), dim3(512), smem2, stream>>>(
            Cg, wsLog, nullptr, Wout, Aout);
    } else {
        k1_gemm1_softmaxq<0><<<dim3(NB * 2), dim3(384), 0, stream>>>(Qg, Cg, nullptr, Aout);
        k15_softmaxs<<<dim3(NB, 24), dim3(256), 0, stream>>>(Aout);
        (void)hipFuncSetAttribute((const void*)k2_gemm2<false>,
                                  hipFuncAttributeMaxDynamicSharedMemorySize, smem2);
        k2_gemm2<false><<<dim3(NB * 4), dim3(512), smem2, stream>>>(
            Cg, nullptr, Aout, Wout, Aout);
    }
}